// Round 10
// baseline (280.793 us; speedup 1.0000x reference)
//
#include <hip/hip_runtime.h>
#include <math.h>

#define TOPK 100
#define HW 65536                   // 256*256
#define SLICE_STRIDE (7*HW)        // 458752
#define NBATCH 32
#define NBOX 200
#define HM (3*HW)                  // 196608 heatmap elems per slice
#define CAP 4096                   // candidate cap (no-ws fallback path)
#define NPART 8                    // collect parts per slice
#define PPART 64                   // key slots per part
#define KEYS_BASE 256              // u64 index where keys start (2048B cnt region)
#define WS_NEED ((size_t)(2048 + 64 * NPART * PPART * 8))
#define TKEYS 0xC0400000u          // fkey(3.0f). N(0,1): per-part (24576 elems)
                                   // mean 33.2 sigma 5.75 -> P(>64) ~ 5.5sigma;
                                   // per-slice 265+-16 -> P(<100) ~ 10sigma.
                                   // Exact in-kernel fallback guards regardless.

// Order-preserving float->uint key: f1 > f2  <=>  key(f1) > key(f2)
__device__ __forceinline__ unsigned fkey(float f) {
    unsigned u = __float_as_uint(f);
    return (u & 0x80000000u) ? ~u : (u | 0x80000000u);
}

// Runtime-slot selects over 4-entry register arrays (constant indices only)
__device__ __forceinline__ float sel4(const float a[4], int s) {
    float r = a[0];
    r = (s == 1) ? a[1] : r;
    r = (s == 2) ? a[2] : r;
    r = (s == 3) ? a[3] : r;
    return r;
}
__device__ __forceinline__ int sel4i(const int a[4], int s) {
    int r = a[0];
    r = (s == 1) ? a[1] : r;
    r = (s == 2) ? a[2] : r;
    r = (s == 3) ? a[3] : r;
    return r;
}
__device__ __forceinline__ unsigned sel4u(const unsigned a[4], int s) {
    unsigned r = a[0];
    r = (s == 1) ? a[1] : r;
    r = (s == 2) ? a[2] : r;
    r = (s == 3) ? a[3] : r;
    return r;
}
__device__ __forceinline__ unsigned long long sel4ull(const unsigned long long a[4], int s) {
    unsigned long long r = a[0];
    r = (s == 1) ? a[1] : r;
    r = (s == 2) ? a[2] : r;
    r = (s == 3) ? a[3] : r;
    return r;
}

// ---------------------------------------------------------------------------
// Wave64 u64 max-reduce via DPP (verbatim from rounds 5-9 verified kernels).
// ---------------------------------------------------------------------------
#if defined(__has_builtin) && __has_builtin(__builtin_amdgcn_update_dpp)
#define DPP64_STEP(ctrl)                                                        \
    {                                                                           \
        unsigned lo = (unsigned)x, hi = (unsigned)(x >> 32);                    \
        unsigned olo = (unsigned)__builtin_amdgcn_update_dpp((int)lo, (int)lo,  \
                                                             (ctrl), 0xF, 0xF, false); \
        unsigned ohi = (unsigned)__builtin_amdgcn_update_dpp((int)hi, (int)hi,  \
                                                             (ctrl), 0xF, 0xF, false); \
        unsigned long long o = ((unsigned long long)ohi << 32) | olo;           \
        x = (o > x) ? o : x;                                                    \
    }
__device__ __forceinline__ unsigned long long wave_umax64(unsigned long long x) {
    DPP64_STEP(0x111) DPP64_STEP(0x112) DPP64_STEP(0x114)
    DPP64_STEP(0x118) DPP64_STEP(0x142) DPP64_STEP(0x143)
    unsigned rlo = (unsigned)__builtin_amdgcn_readlane((int)(unsigned)x, 63);
    unsigned rhi = (unsigned)__builtin_amdgcn_readlane((int)(unsigned)(x >> 32), 63);
    return ((unsigned long long)rhi << 32) | rlo;
}
__device__ __forceinline__ int lane_geti(int v, int lane) {
    return __builtin_amdgcn_readlane(v, lane);
}
__device__ __forceinline__ float lane_getf(const float a[4], int slot, int lane) {
    return __uint_as_float((unsigned)__builtin_amdgcn_readlane(
        (int)__float_as_uint(sel4(a, slot)), lane));
}
#else
__device__ __forceinline__ unsigned long long wave_umax64(unsigned long long x) {
    #pragma unroll
    for (int off = 32; off > 0; off >>= 1) {
        unsigned long long o = __shfl_xor(x, off);
        if (o > x) x = o;
    }
    return x;
}
__device__ __forceinline__ int lane_geti(int v, int lane) { return __shfl(v, lane); }
__device__ __forceinline__ float lane_getf(const float a[4], int slot, int lane) {
    return __shfl(sel4(a, slot), lane);
}
#endif

// nt-load (r9-measured): the 48MB heatmap stream is read-once.
typedef __attribute__((ext_vector_type(4))) float f4v;
#if defined(__has_builtin) && __has_builtin(__builtin_nontemporal_load)
#define NT_LOAD(p) __builtin_nontemporal_load(p)
#else
#define NT_LOAD(p) (*(p))
#endif

// ===========================================================================
// Kernel 1: threshold collect (byte-identical to round 9's measured-good
// version: 512 blocks x 1024 threads, private count+key regions per block).
// ===========================================================================
__global__ __launch_bounds__(1024) void kcollect(const float* __restrict__ x,
                                                 unsigned long long* __restrict__ ws) {
    __shared__ unsigned shCnt;
    const int bid = blockIdx.x;
    const int slice = bid >> 3, part = bid & 7;
    const int t = threadIdx.x;
    const float* xb = x + (size_t)slice * SLICE_STRIDE;
    const f4v* xb4 = (const f4v*)xb;
    unsigned* cnt = (unsigned*)ws;                          // u32[64*8]
    unsigned long long* keys = ws + KEYS_BASE;

    if (t == 0) shCnt = 0u;
    __syncthreads();

    const int i0 = part * (HM / 4 / NPART);                 // 6144 float4/part
    const int i1 = i0 + (HM / 4 / NPART);
    for (int i = i0 + t; i < i1; i += 1024) {
        f4v v = NT_LOAD(&xb4[i]);
        float a[4] = {v.x, v.y, v.z, v.w};
        #pragma unroll
        for (int q = 0; q < 4; ++q) {
            unsigned vk = fkey(a[q]);
            if (vk >= TKEYS) {
                unsigned pos = atomicAdd(&shCnt, 1u);
                if (pos < PPART)
                    keys[(size_t)slice * (NPART * PPART) + part * PPART + pos] =
                        ((unsigned long long)vk << 32) |
                        (unsigned)~(unsigned)(i * 4 + q);
            }
        }
    }
    __syncthreads();
    if (t == 0) cnt[slice * NPART + part] = shCnt;          // raw (may > PPART)
}

// ---------------------------------------------------------------------------
// Exact selection fallback (round-0 verified argmax loop; 1024-thread form).
// ---------------------------------------------------------------------------
__device__ void fb_select(const float* xb, unsigned long long* fkrow,
                          unsigned* selmask, float* rv, int* ri, int t) {
    for (int i = t; i < HM / 32; i += 1024) selmask[i] = 0u;
    __syncthreads();
    for (int r = 0; r < TOPK; ++r) {
        float bv = -INFINITY; int bi = 0x7FFFFFFF;
        for (int i = t; i < HM; i += 1024) {
            if (!((selmask[i >> 5] >> (i & 31)) & 1u)) {
                float v = xb[i];
                if (v > bv || (v == bv && i < bi)) { bv = v; bi = i; }
            }
        }
        rv[t] = bv; ri[t] = bi;
        __syncthreads();
        for (int off = 512; off > 0; off >>= 1) {
            if (t < off) {
                float ov = rv[t + off]; int oi = ri[t + off];
                if (ov > rv[t] || (ov == rv[t] && oi < ri[t])) { rv[t] = ov; ri[t] = oi; }
            }
            __syncthreads();
        }
        if (t == 0) {
            int w = ri[0];
            selmask[w >> 5] |= (1u << (w & 31));
            fkrow[r] = ((unsigned long long)fkey(rv[0]) << 32) |
                       (unsigned)~(unsigned)w;
        }
        __syncthreads();
    }
}

// ===========================================================================
// Kernel 2: 32 blocks x 1024 threads.
// Phase A: gather + sort + decode (round-9 verified) + NEW: merged selection
// order morder[] via parallel binary-search merge of the two per-slice
// sorted score lists (any duplicate/zero score -> walkBad -> verified loop).
// Phase B: wave-0 soft-NMS. Common path = M-walk (no wave reduce): winner is
// max(walk front over un-decayed, cached Dmax over decayed); Dmax recomputed
// (one 64-bit reduce) only when the decayed set changes. ANY ambiguity flips
// to the round-9-VERIFIED body from the current exactly-maintained (CP,SC)
// state, before any mutation. Skip-decay ballot is the r7-verified bit-exact
// rule (all inter==0 -> w=expf(-0.0f)=1.0f).
// ===========================================================================
__global__ __launch_bounds__(1024) void knms8(const float* __restrict__ x,
                                              const unsigned long long* __restrict__ ws,
                                              float* __restrict__ out) {
    __shared__ unsigned long long shpool64[4096];   // 32 KB union
    __shared__ unsigned long long fk[2][TOPK];
    __shared__ float4 bxs4[NBOX];
    __shared__ float scs[NBOX];
    __shared__ float cl[NBOX];
    __shared__ int morder[NBOX];
    __shared__ int badf[2];
    __shared__ int walkBad;

    unsigned long long* skey = shpool64;            // [2][512]
    unsigned* selmask = (unsigned*)shpool64;        // fallback: [6144]
    float* rv = (float*)(selmask + 6144);           // fallback: [1024]
    int* ri = (int*)(selmask + 7168);               // fallback: [1024]

    const int b = blockIdx.x, t = threadIdx.x;
    const unsigned* cnt = (const unsigned*)ws;
    const unsigned long long* keys = ws + KEYS_BASE;

    if (t < 2) {
        unsigned tot = 0; int bad = 0;
        for (int p8 = 0; p8 < NPART; ++p8) {
            unsigned c = cnt[(2 * b + t) * NPART + p8];
            tot += c;
            if (c > PPART) bad = 1;
        }
        if (tot < TOPK) bad = 1;
        badf[t] = bad;
    }
    if (t == 0) walkBad = 0;
    __syncthreads();

    if (badf[0]) fb_select(x + (size_t)(2 * b + 0) * SLICE_STRIDE, fk[0],
                           selmask, rv, ri, t);
    if (badf[1]) fb_select(x + (size_t)(2 * b + 1) * SLICE_STRIDE, fk[1],
                           selmask, rv, ri, t);

    // ---- phase A: gather + bitonic sort 512 per half (parallel halves) ----
    const int half = t >> 9, tt = t & 511;
    const int slice = 2 * b + half;
    {
        int part = tt >> 6, off = tt & 63;          // NPART=8 x PPART=64
        unsigned c = cnt[slice * NPART + part];
        bool valid = (!badf[half]) && ((unsigned)off < c);
        skey[half * 512 + tt] = valid
            ? keys[(size_t)slice * (NPART * PPART) + part * PPART + off] : 0ull;
    }
    __syncthreads();
    for (int k = 2; k <= 512; k <<= 1) {
        for (int j = k >> 1; j > 0; j >>= 1) {
            int i = tt, ixj = i ^ j;
            if (ixj > i) {
                unsigned long long a = skey[half * 512 + i];
                unsigned long long c2 = skey[half * 512 + ixj];
                bool sw = ((i & k) == 0) ? (a < c2) : (a > c2);
                if (sw) { skey[half * 512 + i] = c2; skey[half * 512 + ixj] = a; }
            }
            __syncthreads();
        }
    }

    // ---- decode top-100 per slice (formulas verbatim, verified r2-r9) ----
    if (t < NBOX) {
        const int sB = t / TOPK, rank = t - sB * TOPK;
        const int sl2 = 2 * b + sB;
        unsigned long long K = badf[sB] ? fk[sB][rank] : skey[sB * 512 + rank];
        unsigned vk = (unsigned)(K >> 32);
        unsigned idx = ~((unsigned)K);
        unsigned u = (vk & 0x80000000u) ? (vk & 0x7FFFFFFFu) : ~vk;
        float z = __uint_as_float(u);               // exact original logit
        int c = (int)(idx >> 16);                   // HW == 2^16
        int rem = (int)(idx & 0xFFFFu);
        const float* xb = x + (size_t)sl2 * SLICE_STRIDE;
        float ysf = (float)(rem >> 8);
        float xsf = (float)(rem & 255);
        float offx = xb[3 * HW + rem];
        float offy = xb[4 * HW + rem];
        float bw = xb[5 * HW + rem] * 4.0f;
        float bh = xb[6 * HW + rem] * 4.0f;
        float cx = (xsf + offx) * 4.0f;
        float cy = (ysf + offy) * 4.0f;
        bxs4[t] = make_float4(cx - bw * 0.5f, cy - bh * 0.5f,
                              cx + bw * 0.5f, cy + bh * 0.5f);
        float sg = 1.0f / (1.0f + expf(-z));
        scs[t] = (sg > 0.1f) ? sg : 0.0f;
        cl[t] = (float)c;
    }
    __syncthreads();

    // ---- merged selection order (valid iff all 200 scores distinct, >0) ----
    if (t < NBOX) {
        const int sB = t / TOPK, rank = t - sB * TOPK;
        unsigned sb = __float_as_uint(scs[t]);      // scores >= 0: bit order ok
        if (sb == 0u) walkBad = 1;
        if (rank > 0 && __float_as_uint(scs[t - 1]) == sb) walkBad = 1;
        const int o0 = (1 - sB) * TOPK;             // other (desc-sorted) list
        int lo = 0, hi = TOPK;                      // # strictly greater
        while (lo < hi) {
            int mid = (lo + hi) >> 1;
            unsigned obt = __float_as_uint(scs[o0 + mid]);
            if (obt > sb) lo = mid + 1; else hi = mid;
        }
        if (lo < TOPK && __float_as_uint(scs[o0 + lo]) == sb) walkBad = 1;
        morder[rank + lo] = t;                      // permutation iff distinct
    }
    __syncthreads();

    // ---- phase B: wave 0 only ----
    if (t < 64) {
        float X1[4], Y1[4], X2[4], Y2[4], SC[4], CL4[4], AR[4];
        unsigned CP[4];
        int M4[4];
        #pragma unroll
        for (int sl = 0; sl < 4; ++sl) {
            int p = sl * 64 + t;
            int q = (p < NBOX) ? p : 0;
            float4 bb = bxs4[q];
            X1[sl] = bb.x; Y1[sl] = bb.y; X2[sl] = bb.z; Y2[sl] = bb.w;
            SC[sl] = (p < NBOX) ? scs[q] : 0.0f;    // phantoms: score 0
            CL4[sl] = cl[q];
            CP[sl] = (unsigned)p;                   // phantoms: cpos 200..255
            AR[sl] = (X2[sl] - X1[sl] + 1.0f) * (Y2[sl] - Y1[sl] + 1.0f);
            M4[sl] = (p < NBOX) ? morder[p] : 0;
        }

        bool useWalk = (walkBad == 0);
        unsigned long long takenM[4] = {0ull, 0ull, 0ull, 0ull};
        unsigned long long dirtyM[4] = {0ull, 0ull, 0ull, 0ull};
        int mi = 0;
        int Dcnt = 0, Dp = -1;
        unsigned DmaxSb = 0u;

        for (int i = 0; i < NBOX; ++i) {
            const unsigned ui = (unsigned)i;

            if (useWalk) {
                // ---- walk front: first morder entry not taken & not dirty ----
                int fp = -1;
                while (mi < NBOX) {
                    int cand2 = lane_geti(sel4i(M4, mi >> 6), mi & 63);
                    unsigned long long blk =
                        sel4ull(takenM, cand2 >> 6) | sel4ull(dirtyM, cand2 >> 6);
                    if ((blk >> (cand2 & 63)) & 1ull) { ++mi; continue; }
                    fp = cand2; break;
                }
                int winner = fp; bool fromD = false;
                if (Dcnt > 0) {
                    unsigned fsb = 0u;
                    if (fp >= 0)
                        fsb = (unsigned)lane_geti(
                            (int)__float_as_uint(sel4(SC, fp >> 6)), fp & 63);
                    if (fp >= 0 && fsb == DmaxSb) {
                        useWalk = false;            // score tie front vs Dmax
                    } else if (fp < 0 || DmaxSb > fsb) {
                        winner = Dp; fromD = true;
                    }
                }
                if (useWalk) {
                    const int wl = winner & 63, wsl = winner >> 6;
                    unsigned m = (unsigned)lane_geti((int)sel4u(CP, wsl), wl);
                    float pvx1 = lane_getf(X1, wsl, wl);
                    float pvy1 = lane_getf(Y1, wsl, wl);
                    float pvx2 = lane_getf(X2, wsl, wl);
                    float pvy2 = lane_getf(Y2, wsl, wl);
                    float area_i = lane_getf(AR, wsl, wl);

                    // virtual swap: pos i <-> pos m (identical to verified)
                    #pragma unroll
                    for (int sl = 0; sl < 4; ++sl) {
                        unsigned cp = CP[sl];
                        unsigned ncp = (cp == ui) ? m : cp;
                        ncp = (cp == m) ? ui : ncp;
                        CP[sl] = ncp;
                    }
                    if (fromD) takenM[wsl] |= (1ull << wl);
                    else ++mi;                      // front consumed

                    // intersection + overlap ballot (r7-verified skip rule)
                    float intr[4]; bool act[4]; bool anyp = false;
                    #pragma unroll
                    for (int sl = 0; sl < 4; ++sl) {
                        int p = sl * 64 + t;
                        act[sl] = (p < NBOX) && (CP[sl] > ui);
                        float xx1 = fmaxf(pvx1, X1[sl]);
                        float yy1 = fmaxf(pvy1, Y1[sl]);
                        float xx2 = fminf(pvx2, X2[sl]);
                        float yy2 = fminf(pvy2, Y2[sl]);
                        float inter = fmaxf(0.0f, xx2 - xx1 + 1.0f) *
                                      fmaxf(0.0f, yy2 - yy1 + 1.0f);
                        intr[sl] = inter;
                        anyp |= (act[sl] && inter != 0.0f);
                    }
                    bool needD = fromD;
                    if (__ballot(anyp) != 0ull) {
                        bool dec[4];
                        #pragma unroll
                        for (int sl = 0; sl < 4; ++sl) {
                            dec[sl] = act[sl] && (intr[sl] != 0.0f);
                            if (dec[sl]) {
                                float iou = intr[sl] / (area_i + AR[sl] - intr[sl]);
                                float w = expf(-(iou * iou) / 0.5f);
                                SC[sl] = w * SC[sl];
                            }
                        }
                        #pragma unroll
                        for (int sl = 0; sl < 4; ++sl)
                            dirtyM[sl] |= __ballot(dec[sl]);
                        needD = true;
                    }
                    if (needD) {
                        // ---- Dmax recompute (rare): one 64-bit reduce ----
                        unsigned long long Dm[4];
                        #pragma unroll
                        for (int sl = 0; sl < 4; ++sl)
                            Dm[sl] = dirtyM[sl] & ~takenM[sl];
                        Dcnt = __popcll(Dm[0]) + __popcll(Dm[1]) +
                               __popcll(Dm[2]) + __popcll(Dm[3]);
                        if (Dcnt == 0) { DmaxSb = 0u; Dp = -1; }
                        else {
                            unsigned long long loc = 0ull;
                            bool mem[4];
                            #pragma unroll
                            for (int sl = 0; sl < 4; ++sl) {
                                mem[sl] = (Dm[sl] >> t) & 1ull;
                                if (mem[sl]) {
                                    unsigned cd = ~((CP[sl] << 8) |
                                                    (unsigned)(sl * 64 + t));
                                    unsigned long long kk =
                                        ((unsigned long long)
                                         __float_as_uint(SC[sl]) << 32) | cd;
                                    if (kk > loc) loc = kk;
                                }
                            }
                            unsigned long long kd = wave_umax64(loc);
                            DmaxSb = (unsigned)(kd >> 32);
                            Dp = (int)((~((unsigned)kd)) & 0xFFu);
                            // tie inside D at the max -> verified mode next
                            int lt = 0;
                            #pragma unroll
                            for (int sl = 0; sl < 4; ++sl)
                                if (mem[sl] && __float_as_uint(SC[sl]) == DmaxSb) ++lt;
                            unsigned long long b1 = __ballot(lt >= 1);
                            unsigned long long b2 = __ballot(lt >= 2);
                            if (b2 != 0ull || __popcll(b1) > 1) useWalk = false;
                        }
                    }
                    continue;                       // next round
                }
                // fell through with useWalk=false and NO state mutated:
                // run the verified body for this same i.
            }

            // ======= round-9 VERIFIED body (64-bit reduce, verbatim) =======
            unsigned long long loc = 0ull;
            #pragma unroll
            for (int sl = 0; sl < 4; ++sl) {
                unsigned cd = ~((CP[sl] << 8) | (unsigned)(sl * 64 + t));
                unsigned long long k =
                    ((unsigned long long)__float_as_uint(SC[sl]) << 32) | cd;
                if (CP[sl] >= ui && k > loc) loc = k;
            }
            unsigned long long kmax = wave_umax64(loc);
            if ((unsigned)(kmax >> 32) == 0u) break;    // exact early-out (r6/r7)

            unsigned w32 = ~((unsigned)kmax);           // (m<<8)|worig
            unsigned m = w32 >> 8;
            int worig = (int)(w32 & 0xFFu);
            int lane_m = worig & 63, slot_m = worig >> 6;

            float pvx1 = lane_getf(X1, slot_m, lane_m);
            float pvy1 = lane_getf(Y1, slot_m, lane_m);
            float pvx2 = lane_getf(X2, slot_m, lane_m);
            float pvy2 = lane_getf(Y2, slot_m, lane_m);
            float area_i = lane_getf(AR, slot_m, lane_m);

            #pragma unroll
            for (int sl = 0; sl < 4; ++sl) {
                unsigned cp = CP[sl];
                unsigned ncp = (cp == ui) ? m : cp;
                ncp = (cp == m) ? ui : ncp;
                CP[sl] = ncp;
            }

            float intr[4]; bool anyp = false;
            #pragma unroll
            for (int sl = 0; sl < 4; ++sl) {
                int p = sl * 64 + t;
                bool act2 = (p < NBOX) && (CP[sl] > ui);
                float xx1 = fmaxf(pvx1, X1[sl]);
                float yy1 = fmaxf(pvy1, Y1[sl]);
                float xx2 = fminf(pvx2, X2[sl]);
                float yy2 = fminf(pvy2, Y2[sl]);
                float inter = fmaxf(0.0f, xx2 - xx1 + 1.0f) *
                              fmaxf(0.0f, yy2 - yy1 + 1.0f);
                intr[sl] = inter;
                anyp |= (act2 && inter != 0.0f);
            }
            if (__ballot(anyp) != 0ull) {
                #pragma unroll
                for (int sl = 0; sl < 4; ++sl) {
                    int p = sl * 64 + t;
                    if ((p < NBOX) && (CP[sl] > ui)) {
                        float iou = intr[sl] / (area_i + AR[sl] - intr[sl]);
                        float w = expf(-(iou * iou) / 0.5f);
                        SC[sl] = w * SC[sl];
                    }
                }
            }
        }

        // ---- write outputs: box with final cpos q lands at position q ----
        float* ob  = out + (size_t)b * NBOX * 4;
        float* oc  = out + (size_t)NBATCH * NBOX * 4 + b * NBOX;
        float* os  = out + (size_t)NBATCH * NBOX * 5 + b * NBOX;
        float* okp = out + (size_t)NBATCH * NBOX * 6 + b * NBOX;
        #pragma unroll
        for (int sl = 0; sl < 4; ++sl) {
            int p = sl * 64 + t;
            if (p < NBOX) {
                unsigned q = CP[sl];
                ob[q * 4 + 0] = X1[sl];
                ob[q * 4 + 1] = Y1[sl];
                ob[q * 4 + 2] = X2[sl];
                ob[q * 4 + 3] = Y2[sl];
                oc[q]  = CL4[sl];
                os[q]  = SC[sl];
                okp[q] = (SC[sl] > 0.1f) ? 1.0f : 0.0f;
            }
        }
    }
}

// ===========================================================================
// FALLBACK PATH (round-2 verified kernels, verbatim) — used if ws too small
// ===========================================================================
__global__ __launch_bounds__(1024) void ktopk(const float* __restrict__ x,
                                              float* __restrict__ out) {
    __shared__ unsigned hist[4096];
    __shared__ unsigned long long cand[CAP];
    __shared__ int shB, shB2;
    __shared__ unsigned shAbove, shNcand, shNc;

    const int slice = blockIdx.x;
    const int b = slice >> 1, s = slice & 1;
    const int t = threadIdx.x;
    const float* xb = x + (size_t)slice * SLICE_STRIDE;
    const float4* xb4 = (const float4*)xb;
    const int N4 = HM / 4;

    if (t == 0) { shB = 0; shB2 = 0; shAbove = 0u; shNcand = 0u; shNc = 0u; }
    for (int i = t; i < 4096; i += 1024) hist[i] = 0u;
    __syncthreads();

    for (int i = t; i < N4; i += 1024) {
        float4 v = xb4[i];
        float a[4] = {v.x, v.y, v.z, v.w};
        #pragma unroll
        for (int c_ = 0; c_ < 4; ++c_) {
            unsigned vk = fkey(a[c_]);
            atomicAdd(&hist[vk >> 20], 1u);
        }
    }
    __syncthreads();

    {
        unsigned* tmp = (unsigned*)cand;
        unsigned* src = hist;
        unsigned* dst = tmp;
        for (int d = 1; d < 4096; d <<= 1) {
            for (int i = t; i < 4096; i += 1024) {
                unsigned v = src[i];
                if (i + d < 4096) v += src[i + d];
                dst[i] = v;
            }
            __syncthreads();
            unsigned* sw = src; src = dst; dst = sw;
        }
        for (int i = t; i < 4096; i += 1024) {
            unsigned sb = src[i];
            unsigned sn = (i < 4095) ? src[i + 1] : 0u;
            if (sb >= TOPK && sn < TOPK) { shB = i; shAbove = sn; shNcand = sb; }
        }
        __syncthreads();
    }

    const bool refine = (shNcand > CAP);
    if (refine) {
        for (int i = t; i < 4096; i += 1024) hist[i] = 0u;
        __syncthreads();
        const unsigned Bv = (unsigned)shB;
        for (int i = t; i < N4; i += 1024) {
            float4 v = xb4[i];
            float a[4] = {v.x, v.y, v.z, v.w};
            #pragma unroll
            for (int c_ = 0; c_ < 4; ++c_) {
                unsigned vk = fkey(a[c_]);
                if ((vk >> 20) == Bv) atomicAdd(&hist[(vk >> 8) & 0xFFFu], 1u);
            }
        }
        __syncthreads();
        if (t == 0) {
            unsigned need = TOPK - shAbove, cum = 0u;
            int b2 = 4095;
            for (; b2 >= 0; --b2) { cum += hist[b2]; if (cum >= need) break; }
            shB2 = (b2 < 0) ? 0 : b2;
            shNcand = shAbove + cum;
        }
        __syncthreads();
    }

    {
        const unsigned Bv = (unsigned)shB;
        const unsigned B2v = refine ? (unsigned)shB2 : 0u;
        for (int i = t; i < N4; i += 1024) {
            float4 v = xb4[i];
            float a[4] = {v.x, v.y, v.z, v.w};
            #pragma unroll
            for (int c_ = 0; c_ < 4; ++c_) {
                unsigned vk = fkey(a[c_]);
                unsigned bin = vk >> 20;
                bool q = refine ? (bin > Bv || (bin == Bv && ((vk >> 8) & 0xFFFu) >= B2v))
                                : (bin >= Bv);
                if (q) {
                    unsigned pos = atomicAdd(&shNc, 1u);
                    if (pos < CAP)
                        cand[pos] = ((unsigned long long)vk << 32) |
                                    (unsigned)~(unsigned)(i * 4 + c_);
                }
            }
        }
        __syncthreads();
    }

    unsigned nc = shNc; if (nc > CAP) nc = CAP;
    int P = 128; while (P < (int)nc) P <<= 1;
    for (int i = (int)nc + t; i < P; i += 1024) cand[i] = 0ull;
    __syncthreads();
    for (int k = 2; k <= P; k <<= 1) {
        for (int j = k >> 1; j > 0; j >>= 1) {
            for (int i = t; i < P; i += 1024) {
                int ixj = i ^ j;
                if (ixj > i) {
                    unsigned long long a = cand[i], c2 = cand[ixj];
                    bool sw = ((i & k) == 0) ? (a < c2) : (a > c2);
                    if (sw) { cand[i] = c2; cand[ixj] = a; }
                }
            }
            __syncthreads();
        }
    }

    if (t < TOPK) {
        unsigned long long K = cand[t];
        unsigned vk = (unsigned)(K >> 32);
        unsigned idx = ~((unsigned)K);
        unsigned u = (vk & 0x80000000u) ? (vk & 0x7FFFFFFFu) : ~vk;
        float z = __uint_as_float(u);
        int c = (int)(idx >> 16);
        int rem = (int)(idx & 0xFFFFu);
        float ysf = (float)(rem >> 8);
        float xsf = (float)(rem & 255);
        float offx = xb[3 * HW + rem];
        float offy = xb[4 * HW + rem];
        float bw = xb[5 * HW + rem] * 4.0f;
        float bh = xb[6 * HW + rem] * 4.0f;
        float cx = (xsf + offx) * 4.0f;
        float cy = (ysf + offy) * 4.0f;
        int slot = s * TOPK + t;
        float* ob = out + (size_t)b * NBOX * 4;
        float* oc = out + (size_t)NBATCH * NBOX * 4 + b * NBOX;
        float* os = out + (size_t)NBATCH * NBOX * 5 + b * NBOX;
        ob[slot * 4 + 0] = cx - bw * 0.5f;
        ob[slot * 4 + 1] = cy - bh * 0.5f;
        ob[slot * 4 + 2] = cx + bw * 0.5f;
        ob[slot * 4 + 3] = cy + bh * 0.5f;
        float sg = 1.0f / (1.0f + expf(-z));
        os[slot] = (sg > 0.1f) ? sg : 0.0f;
        oc[slot] = (float)c;
    }
}

__global__ __launch_bounds__(64) void knms(float* __restrict__ out) {
    __shared__ float bxs[NBOX][4];
    __shared__ float scs[NBOX];
    __shared__ float cl[NBOX];

    const int b = blockIdx.x, t = threadIdx.x;
    float* ob  = out + (size_t)b * NBOX * 4;
    float* oc  = out + (size_t)NBATCH * NBOX * 4 + b * NBOX;
    float* os  = out + (size_t)NBATCH * NBOX * 5 + b * NBOX;
    float* okp = out + (size_t)NBATCH * NBOX * 6 + b * NBOX;

    for (int p = t; p < NBOX; p += 64) {
        bxs[p][0] = ob[p * 4 + 0];
        bxs[p][1] = ob[p * 4 + 1];
        bxs[p][2] = ob[p * 4 + 2];
        bxs[p][3] = ob[p * 4 + 3];
        scs[p] = os[p];
        cl[p]  = oc[p];
    }
    __syncthreads();

    unsigned long long local = 0ull;
    for (int p = t; p < NBOX; p += 64) {
        unsigned long long k =
            ((unsigned long long)__float_as_uint(scs[p]) << 32) | (unsigned)~(unsigned)p;
        if (k > local) local = k;
    }
    #pragma unroll
    for (int off = 32; off > 0; off >>= 1) {
        unsigned long long o = __shfl_xor(local, off);
        if (o > local) local = o;
    }
    unsigned long long kmax = local;

    for (int i = 0; i < NBOX; ++i) {
        int m = (int)(~((unsigned)kmax));
        if (t == 0 && m != i) {
            #pragma unroll
            for (int k = 0; k < 4; ++k) {
                float tmp = bxs[i][k]; bxs[i][k] = bxs[m][k]; bxs[m][k] = tmp;
            }
            float ts = scs[i]; scs[i] = scs[m]; scs[m] = ts;
            float tc = cl[i];  cl[i]  = cl[m];  cl[m]  = tc;
        }
        __syncthreads();

        float b0 = bxs[i][0], b1 = bxs[i][1], b2 = bxs[i][2], b3 = bxs[i][3];
        float area_i = (b2 - b0 + 1.0f) * (b3 - b1 + 1.0f);

        local = 0ull;
        for (int p = i + 1 + t; p < NBOX; p += 64) {
            float x1 = bxs[p][0], y1 = bxs[p][1], x2 = bxs[p][2], y2 = bxs[p][3];
            float areas = (x2 - x1 + 1.0f) * (y2 - y1 + 1.0f);
            float xx1 = fmaxf(b0, x1);
            float yy1 = fmaxf(b1, y1);
            float xx2 = fminf(b2, x2);
            float yy2 = fminf(b3, y2);
            float inter = fmaxf(0.0f, xx2 - xx1 + 1.0f) * fmaxf(0.0f, yy2 - yy1 + 1.0f);
            float iou = inter / (area_i + areas - inter);
            float w = expf(-(iou * iou) / 0.5f);
            float ns = w * scs[p];
            scs[p] = ns;
            unsigned long long k =
                ((unsigned long long)__float_as_uint(ns) << 32) | (unsigned)~(unsigned)p;
            if (k > local) local = k;
        }
        __syncthreads();
        #pragma unroll
        for (int off = 32; off > 0; off >>= 1) {
            unsigned long long o = __shfl_xor(local, off);
            if (o > local) local = o;
        }
        kmax = local;
    }
    __syncthreads();

    for (int p = t; p < NBOX; p += 64) {
        ob[p * 4 + 0] = bxs[p][0];
        ob[p * 4 + 1] = bxs[p][1];
        ob[p * 4 + 2] = bxs[p][2];
        ob[p * 4 + 3] = bxs[p][3];
        oc[p]  = cl[p];
        os[p]  = scs[p];
        okp[p] = (scs[p] > 0.1f) ? 1.0f : 0.0f;
    }
}

extern "C" void kernel_launch(void* const* d_in, const int* in_sizes, int n_in,
                              void* d_out, int out_size, void* d_ws, size_t ws_size,
                              hipStream_t stream) {
    const float* x = (const float*)d_in[0];
    float* out = (float*)d_out;
    if (d_ws != nullptr && ws_size >= WS_NEED) {
        kcollect<<<64 * NPART, 1024, 0, stream>>>(x, (unsigned long long*)d_ws);
        knms8<<<NBATCH, 1024, 0, stream>>>(x, (const unsigned long long*)d_ws, out);
    } else {
        ktopk<<<2 * NBATCH, 1024, 0, stream>>>(x, out);
        knms<<<NBATCH, 64, 0, stream>>>(out);
    }
}

// Round 11
// 262.811 us; speedup vs baseline: 1.0684x; 1.0684x over previous
//
#include <hip/hip_runtime.h>
#include <math.h>

#define TOPK 100
#define HW 65536                   // 256*256
#define SLICE_STRIDE (7*HW)        // 458752
#define NBATCH 32
#define NBOX 200
#define HM (3*HW)                  // 196608 heatmap elems per slice
#define CAP 4096                   // candidate cap (no-ws fallback path)
#define NPART 8                    // collect parts per slice
#define PPART 64                   // key slots per part
#define KEYS_BASE 256              // u64 index where keys start (2048B cnt region)
#define WS_NEED ((size_t)(2048 + 64 * NPART * PPART * 8))
#define TKEYS 0xC0400000u          // fkey(3.0f). N(0,1): per-part (24576 elems)
                                   // mean 33.2 sigma 5.75 -> P(>64) ~ 5.5sigma;
                                   // per-slice 265+-16 -> P(<100) ~ 10sigma.
                                   // Exact in-kernel fallback guards regardless.

// Order-preserving float->uint key: f1 > f2  <=>  key(f1) > key(f2)
__device__ __forceinline__ unsigned fkey(float f) {
    unsigned u = __float_as_uint(f);
    return (u & 0x80000000u) ? ~u : (u | 0x80000000u);
}

// Runtime-slot select over a 4-entry register array (constant indices only)
__device__ __forceinline__ float sel4(const float a[4], int s) {
    float r = a[0];
    r = (s == 1) ? a[1] : r;
    r = (s == 2) ? a[2] : r;
    r = (s == 3) ? a[3] : r;
    return r;
}

// ---------------------------------------------------------------------------
// Wave64 u64 max-reduce via DPP (verbatim from rounds 5-9 verified kernels).
// ---------------------------------------------------------------------------
#if defined(__has_builtin) && __has_builtin(__builtin_amdgcn_update_dpp)
#define DPP64_STEP(ctrl)                                                        \
    {                                                                           \
        unsigned lo = (unsigned)x, hi = (unsigned)(x >> 32);                    \
        unsigned olo = (unsigned)__builtin_amdgcn_update_dpp((int)lo, (int)lo,  \
                                                             (ctrl), 0xF, 0xF, false); \
        unsigned ohi = (unsigned)__builtin_amdgcn_update_dpp((int)hi, (int)hi,  \
                                                             (ctrl), 0xF, 0xF, false); \
        unsigned long long o = ((unsigned long long)ohi << 32) | olo;           \
        x = (o > x) ? o : x;                                                    \
    }
__device__ __forceinline__ unsigned long long wave_umax64(unsigned long long x) {
    DPP64_STEP(0x111) DPP64_STEP(0x112) DPP64_STEP(0x114)
    DPP64_STEP(0x118) DPP64_STEP(0x142) DPP64_STEP(0x143)
    unsigned rlo = (unsigned)__builtin_amdgcn_readlane((int)(unsigned)x, 63);
    unsigned rhi = (unsigned)__builtin_amdgcn_readlane((int)(unsigned)(x >> 32), 63);
    return ((unsigned long long)rhi << 32) | rlo;
}
__device__ __forceinline__ float lane_getf(const float a[4], int slot, int lane) {
    return __uint_as_float((unsigned)__builtin_amdgcn_readlane(
        (int)__float_as_uint(sel4(a, slot)), lane));
}
#else
__device__ __forceinline__ unsigned long long wave_umax64(unsigned long long x) {
    #pragma unroll
    for (int off = 32; off > 0; off >>= 1) {
        unsigned long long o = __shfl_xor(x, off);
        if (o > x) x = o;
    }
    return x;
}
__device__ __forceinline__ float lane_getf(const float a[4], int slot, int lane) {
    return __shfl(sel4(a, slot), lane);
}
#endif

// nt-load experiment (isolated vs the round-7 274us baseline): the 48MB
// heatmap stream is read-once -> bypass L2 retention with a nontemporal hint.
typedef __attribute__((ext_vector_type(4))) float f4v;
#if defined(__has_builtin) && __has_builtin(__builtin_nontemporal_load)
#define NT_LOAD(p) __builtin_nontemporal_load(p)
#else
#define NT_LOAD(p) (*(p))
#endif

// ===========================================================================
// Kernel 1: threshold collect (round-8 shape: 512 blocks x 1024 threads;
// block (slice,part) exclusively owns cnt[slice*8+part] and its key region —
// no cross-block atomics, no pre-zeroing; reads guarded by counts).
// ===========================================================================
__global__ __launch_bounds__(1024) void kcollect(const float* __restrict__ x,
                                                 unsigned long long* __restrict__ ws) {
    __shared__ unsigned shCnt;
    const int bid = blockIdx.x;
    const int slice = bid >> 3, part = bid & 7;
    const int t = threadIdx.x;
    const float* xb = x + (size_t)slice * SLICE_STRIDE;
    const f4v* xb4 = (const f4v*)xb;
    unsigned* cnt = (unsigned*)ws;                          // u32[64*8]
    unsigned long long* keys = ws + KEYS_BASE;

    if (t == 0) shCnt = 0u;
    __syncthreads();

    const int i0 = part * (HM / 4 / NPART);                 // 6144 float4/part
    const int i1 = i0 + (HM / 4 / NPART);
    for (int i = i0 + t; i < i1; i += 1024) {
        f4v v = NT_LOAD(&xb4[i]);
        float a[4] = {v.x, v.y, v.z, v.w};
        #pragma unroll
        for (int q = 0; q < 4; ++q) {
            unsigned vk = fkey(a[q]);
            if (vk >= TKEYS) {
                unsigned pos = atomicAdd(&shCnt, 1u);
                if (pos < PPART)
                    keys[(size_t)slice * (NPART * PPART) + part * PPART + pos] =
                        ((unsigned long long)vk << 32) |
                        (unsigned)~(unsigned)(i * 4 + q);
            }
        }
    }
    __syncthreads();
    if (t == 0) cnt[slice * NPART + part] = shCnt;          // raw (may > PPART)
}

// ---------------------------------------------------------------------------
// Exact selection fallback (round-0 verified argmax loop; 1024-thread form).
// ---------------------------------------------------------------------------
__device__ void fb_select(const float* xb, unsigned long long* fkrow,
                          unsigned* selmask, float* rv, int* ri, int t) {
    for (int i = t; i < HM / 32; i += 1024) selmask[i] = 0u;
    __syncthreads();
    for (int r = 0; r < TOPK; ++r) {
        float bv = -INFINITY; int bi = 0x7FFFFFFF;
        for (int i = t; i < HM; i += 1024) {
            if (!((selmask[i >> 5] >> (i & 31)) & 1u)) {
                float v = xb[i];
                if (v > bv || (v == bv && i < bi)) { bv = v; bi = i; }
            }
        }
        rv[t] = bv; ri[t] = bi;
        __syncthreads();
        for (int off = 512; off > 0; off >>= 1) {
            if (t < off) {
                float ov = rv[t + off]; int oi = ri[t + off];
                if (ov > rv[t] || (ov == rv[t] && oi < ri[t])) { rv[t] = ov; ri[t] = oi; }
            }
            __syncthreads();
        }
        if (t == 0) {
            int w = ri[0];
            selmask[w >> 5] |= (1u << (w & 31));
            fkrow[r] = ((unsigned long long)fkey(rv[0]) << 32) |
                       (unsigned)~(unsigned)w;
        }
        __syncthreads();
    }
}

// ===========================================================================
// Kernel 2 (round-7 verified knms6, verbatim; gather adapted to NPART=8).
// 32 blocks x 1024 threads. Phase A: per half-block, gather <=512 keys,
// bitonic sort, decode top-100 per slice. Phase B: wave-0 virtual-position
// soft-NMS with decay-skip ballot (all inter==0 -> w=expf(-0.0f)=1.0f ->
// skip is bit-exact) and exact zero-score early-out.
// ===========================================================================
__global__ __launch_bounds__(1024) void knms6(const float* __restrict__ x,
                                              const unsigned long long* __restrict__ ws,
                                              float* __restrict__ out) {
    __shared__ unsigned long long shpool64[4096];   // 32 KB union
    __shared__ unsigned long long fk[2][TOPK];
    __shared__ float4 bxs4[NBOX];
    __shared__ float scs[NBOX];
    __shared__ float cl[NBOX];
    __shared__ int badf[2];

    unsigned long long* skey = shpool64;            // [2][512]
    unsigned* selmask = (unsigned*)shpool64;        // fallback: [6144]
    float* rv = (float*)(selmask + 6144);           // fallback: [1024]
    int* ri = (int*)(selmask + 7168);               // fallback: [1024]

    const int b = blockIdx.x, t = threadIdx.x;
    const unsigned* cnt = (const unsigned*)ws;
    const unsigned long long* keys = ws + KEYS_BASE;

    if (t < 2) {
        unsigned tot = 0; int bad = 0;
        for (int p8 = 0; p8 < NPART; ++p8) {
            unsigned c = cnt[(2 * b + t) * NPART + p8];
            tot += c;
            if (c > PPART) bad = 1;
        }
        if (tot < TOPK) bad = 1;
        badf[t] = bad;
    }
    __syncthreads();

    if (badf[0]) fb_select(x + (size_t)(2 * b + 0) * SLICE_STRIDE, fk[0],
                           selmask, rv, ri, t);
    if (badf[1]) fb_select(x + (size_t)(2 * b + 1) * SLICE_STRIDE, fk[1],
                           selmask, rv, ri, t);

    // ---- phase A: gather + bitonic sort 512 per half (parallel halves) ----
    const int half = t >> 9, tt = t & 511;
    const int slice = 2 * b + half;
    {
        int part = tt >> 6, off = tt & 63;          // NPART=8 x PPART=64
        unsigned c = cnt[slice * NPART + part];
        bool valid = (!badf[half]) && ((unsigned)off < c);
        skey[half * 512 + tt] = valid
            ? keys[(size_t)slice * (NPART * PPART) + part * PPART + off] : 0ull;
    }
    __syncthreads();
    for (int k = 2; k <= 512; k <<= 1) {
        for (int j = k >> 1; j > 0; j >>= 1) {
            int i = tt, ixj = i ^ j;
            if (ixj > i) {
                unsigned long long a = skey[half * 512 + i];
                unsigned long long c2 = skey[half * 512 + ixj];
                bool sw = ((i & k) == 0) ? (a < c2) : (a > c2);
                if (sw) { skey[half * 512 + i] = c2; skey[half * 512 + ixj] = a; }
            }
            __syncthreads();
        }
    }

    // ---- decode top-100 per slice (formulas verbatim, verified r2-r7) ----
    if (t < NBOX) {
        const int sB = t / TOPK, rank = t - sB * TOPK;
        const int sl2 = 2 * b + sB;
        unsigned long long K = badf[sB] ? fk[sB][rank] : skey[sB * 512 + rank];
        unsigned vk = (unsigned)(K >> 32);
        unsigned idx = ~((unsigned)K);
        unsigned u = (vk & 0x80000000u) ? (vk & 0x7FFFFFFFu) : ~vk;
        float z = __uint_as_float(u);               // exact original logit
        int c = (int)(idx >> 16);                   // HW == 2^16
        int rem = (int)(idx & 0xFFFFu);
        const float* xb = x + (size_t)sl2 * SLICE_STRIDE;
        float ysf = (float)(rem >> 8);
        float xsf = (float)(rem & 255);
        float offx = xb[3 * HW + rem];
        float offy = xb[4 * HW + rem];
        float bw = xb[5 * HW + rem] * 4.0f;
        float bh = xb[6 * HW + rem] * 4.0f;
        float cx = (xsf + offx) * 4.0f;
        float cy = (ysf + offy) * 4.0f;
        bxs4[t] = make_float4(cx - bw * 0.5f, cy - bh * 0.5f,
                              cx + bw * 0.5f, cy + bh * 0.5f);
        float sg = 1.0f / (1.0f + expf(-z));
        scs[t] = (sg > 0.1f) ? sg : 0.0f;
        cl[t] = (float)c;
    }
    __syncthreads();

    // ---- phase B: wave 0, virtual-position soft-NMS with decay-skip ----
    if (t < 64) {
        float X1[4], Y1[4], X2[4], Y2[4], SC[4], CL4[4], AR[4];
        unsigned CP[4];
        #pragma unroll
        for (int sl = 0; sl < 4; ++sl) {
            int p = sl * 64 + t;
            int q = (p < NBOX) ? p : 0;
            float4 bb = bxs4[q];
            X1[sl] = bb.x; Y1[sl] = bb.y; X2[sl] = bb.z; Y2[sl] = bb.w;
            SC[sl] = (p < NBOX) ? scs[q] : 0.0f;    // phantoms: score 0
            CL4[sl] = cl[q];
            CP[sl] = (unsigned)p;                   // phantoms: cpos 200..255
            AR[sl] = (X2[sl] - X1[sl] + 1.0f) * (Y2[sl] - Y1[sl] + 1.0f);
        }

        for (int i = 0; i < NBOX; ++i) {
            const unsigned ui = (unsigned)i;
            // 64-bit key (score bits, ~((cpos<<8)|orig)); mask cpos>=i.
            // Real boxes always occupy positions 0..199 -> winner is real.
            unsigned long long loc = 0ull;
            #pragma unroll
            for (int sl = 0; sl < 4; ++sl) {
                unsigned cd = ~((CP[sl] << 8) | (unsigned)(sl * 64 + t));
                unsigned long long k =
                    ((unsigned long long)__float_as_uint(SC[sl]) << 32) | cd;
                if (CP[sl] >= ui && k > loc) loc = k;
            }
            unsigned long long kmax = wave_umax64(loc);

            // exact early-out (verified r6/r7): max remaining +0 -> frozen
            if ((unsigned)(kmax >> 32) == 0u) break;

            unsigned w32 = ~((unsigned)kmax);       // (m<<8)|worig
            unsigned m = w32 >> 8;
            int worig = (int)(w32 & 0xFFu);
            int lane_m = worig & 63, slot_m = worig >> 6;

            float pvx1 = lane_getf(X1, slot_m, lane_m);
            float pvy1 = lane_getf(Y1, slot_m, lane_m);
            float pvx2 = lane_getf(X2, slot_m, lane_m);
            float pvy2 = lane_getf(Y2, slot_m, lane_m);
            float area_i = lane_getf(AR, slot_m, lane_m);

            // virtual swap: pos i <-> pos m
            #pragma unroll
            for (int sl = 0; sl < 4; ++sl) {
                unsigned cp = CP[sl];
                unsigned ncp = (cp == ui) ? m : cp;
                ncp = (cp == m) ? ui : ncp;
                CP[sl] = ncp;
            }

            // intersection prefix + overlap ballot
            float intr[4]; bool anyp = false;
            #pragma unroll
            for (int sl = 0; sl < 4; ++sl) {
                int p = sl * 64 + t;
                bool act = (p < NBOX) && (CP[sl] > ui);
                float xx1 = fmaxf(pvx1, X1[sl]);
                float yy1 = fmaxf(pvy1, Y1[sl]);
                float xx2 = fminf(pvx2, X2[sl]);
                float yy2 = fminf(pvy2, Y2[sl]);
                float inter = fmaxf(0.0f, xx2 - xx1 + 1.0f) *
                              fmaxf(0.0f, yy2 - yy1 + 1.0f);
                intr[sl] = inter;
                anyp |= (act && inter != 0.0f);
            }
            // skip is bit-exact: inter==0 -> iou=0 -> w=expf(-0.0f)=1.0f
            if (__ballot(anyp) != 0ull) {
                #pragma unroll
                for (int sl = 0; sl < 4; ++sl) {
                    int p = sl * 64 + t;
                    if ((p < NBOX) && (CP[sl] > ui)) {
                        float iou = intr[sl] / (area_i + AR[sl] - intr[sl]);
                        float w = expf(-(iou * iou) / 0.5f);
                        SC[sl] = w * SC[sl];
                    }
                }
            }
        }

        // ---- write outputs: box with final cpos q lands at position q ----
        float* ob  = out + (size_t)b * NBOX * 4;
        float* oc  = out + (size_t)NBATCH * NBOX * 4 + b * NBOX;
        float* os  = out + (size_t)NBATCH * NBOX * 5 + b * NBOX;
        float* okp = out + (size_t)NBATCH * NBOX * 6 + b * NBOX;
        #pragma unroll
        for (int sl = 0; sl < 4; ++sl) {
            int p = sl * 64 + t;
            if (p < NBOX) {
                unsigned q = CP[sl];
                ob[q * 4 + 0] = X1[sl];
                ob[q * 4 + 1] = Y1[sl];
                ob[q * 4 + 2] = X2[sl];
                ob[q * 4 + 3] = Y2[sl];
                oc[q]  = CL4[sl];
                os[q]  = SC[sl];
                okp[q] = (SC[sl] > 0.1f) ? 1.0f : 0.0f;
            }
        }
    }
}

// ===========================================================================
// FALLBACK PATH (round-2 verified kernels, verbatim) — used if ws too small
// ===========================================================================
__global__ __launch_bounds__(1024) void ktopk(const float* __restrict__ x,
                                              float* __restrict__ out) {
    __shared__ unsigned hist[4096];
    __shared__ unsigned long long cand[CAP];
    __shared__ int shB, shB2;
    __shared__ unsigned shAbove, shNcand, shNc;

    const int slice = blockIdx.x;
    const int b = slice >> 1, s = slice & 1;
    const int t = threadIdx.x;
    const float* xb = x + (size_t)slice * SLICE_STRIDE;
    const float4* xb4 = (const float4*)xb;
    const int N4 = HM / 4;

    if (t == 0) { shB = 0; shB2 = 0; shAbove = 0u; shNcand = 0u; shNc = 0u; }
    for (int i = t; i < 4096; i += 1024) hist[i] = 0u;
    __syncthreads();

    for (int i = t; i < N4; i += 1024) {
        float4 v = xb4[i];
        float a[4] = {v.x, v.y, v.z, v.w};
        #pragma unroll
        for (int c_ = 0; c_ < 4; ++c_) {
            unsigned vk = fkey(a[c_]);
            atomicAdd(&hist[vk >> 20], 1u);
        }
    }
    __syncthreads();

    {
        unsigned* tmp = (unsigned*)cand;
        unsigned* src = hist;
        unsigned* dst = tmp;
        for (int d = 1; d < 4096; d <<= 1) {
            for (int i = t; i < 4096; i += 1024) {
                unsigned v = src[i];
                if (i + d < 4096) v += src[i + d];
                dst[i] = v;
            }
            __syncthreads();
            unsigned* sw = src; src = dst; dst = sw;
        }
        for (int i = t; i < 4096; i += 1024) {
            unsigned sb = src[i];
            unsigned sn = (i < 4095) ? src[i + 1] : 0u;
            if (sb >= TOPK && sn < TOPK) { shB = i; shAbove = sn; shNcand = sb; }
        }
        __syncthreads();
    }

    const bool refine = (shNcand > CAP);
    if (refine) {
        for (int i = t; i < 4096; i += 1024) hist[i] = 0u;
        __syncthreads();
        const unsigned Bv = (unsigned)shB;
        for (int i = t; i < N4; i += 1024) {
            float4 v = xb4[i];
            float a[4] = {v.x, v.y, v.z, v.w};
            #pragma unroll
            for (int c_ = 0; c_ < 4; ++c_) {
                unsigned vk = fkey(a[c_]);
                if ((vk >> 20) == Bv) atomicAdd(&hist[(vk >> 8) & 0xFFFu], 1u);
            }
        }
        __syncthreads();
        if (t == 0) {
            unsigned need = TOPK - shAbove, cum = 0u;
            int b2 = 4095;
            for (; b2 >= 0; --b2) { cum += hist[b2]; if (cum >= need) break; }
            shB2 = (b2 < 0) ? 0 : b2;
            shNcand = shAbove + cum;
        }
        __syncthreads();
    }

    {
        const unsigned Bv = (unsigned)shB;
        const unsigned B2v = refine ? (unsigned)shB2 : 0u;
        for (int i = t; i < N4; i += 1024) {
            float4 v = xb4[i];
            float a[4] = {v.x, v.y, v.z, v.w};
            #pragma unroll
            for (int c_ = 0; c_ < 4; ++c_) {
                unsigned vk = fkey(a[c_]);
                unsigned bin = vk >> 20;
                bool q = refine ? (bin > Bv || (bin == Bv && ((vk >> 8) & 0xFFFu) >= B2v))
                                : (bin >= Bv);
                if (q) {
                    unsigned pos = atomicAdd(&shNc, 1u);
                    if (pos < CAP)
                        cand[pos] = ((unsigned long long)vk << 32) |
                                    (unsigned)~(unsigned)(i * 4 + c_);
                }
            }
        }
        __syncthreads();
    }

    unsigned nc = shNc; if (nc > CAP) nc = CAP;
    int P = 128; while (P < (int)nc) P <<= 1;
    for (int i = (int)nc + t; i < P; i += 1024) cand[i] = 0ull;
    __syncthreads();
    for (int k = 2; k <= P; k <<= 1) {
        for (int j = k >> 1; j > 0; j >>= 1) {
            for (int i = t; i < P; i += 1024) {
                int ixj = i ^ j;
                if (ixj > i) {
                    unsigned long long a = cand[i], c2 = cand[ixj];
                    bool sw = ((i & k) == 0) ? (a < c2) : (a > c2);
                    if (sw) { cand[i] = c2; cand[ixj] = a; }
                }
            }
            __syncthreads();
        }
    }

    if (t < TOPK) {
        unsigned long long K = cand[t];
        unsigned vk = (unsigned)(K >> 32);
        unsigned idx = ~((unsigned)K);
        unsigned u = (vk & 0x80000000u) ? (vk & 0x7FFFFFFFu) : ~vk;
        float z = __uint_as_float(u);
        int c = (int)(idx >> 16);
        int rem = (int)(idx & 0xFFFFu);
        float ysf = (float)(rem >> 8);
        float xsf = (float)(rem & 255);
        float offx = xb[3 * HW + rem];
        float offy = xb[4 * HW + rem];
        float bw = xb[5 * HW + rem] * 4.0f;
        float bh = xb[6 * HW + rem] * 4.0f;
        float cx = (xsf + offx) * 4.0f;
        float cy = (ysf + offy) * 4.0f;
        int slot = s * TOPK + t;
        float* ob = out + (size_t)b * NBOX * 4;
        float* oc = out + (size_t)NBATCH * NBOX * 4 + b * NBOX;
        float* os = out + (size_t)NBATCH * NBOX * 5 + b * NBOX;
        ob[slot * 4 + 0] = cx - bw * 0.5f;
        ob[slot * 4 + 1] = cy - bh * 0.5f;
        ob[slot * 4 + 2] = cx + bw * 0.5f;
        ob[slot * 4 + 3] = cy + bh * 0.5f;
        float sg = 1.0f / (1.0f + expf(-z));
        os[slot] = (sg > 0.1f) ? sg : 0.0f;
        oc[slot] = (float)c;
    }
}

__global__ __launch_bounds__(64) void knms(float* __restrict__ out) {
    __shared__ float bxs[NBOX][4];
    __shared__ float scs[NBOX];
    __shared__ float cl[NBOX];

    const int b = blockIdx.x, t = threadIdx.x;
    float* ob  = out + (size_t)b * NBOX * 4;
    float* oc  = out + (size_t)NBATCH * NBOX * 4 + b * NBOX;
    float* os  = out + (size_t)NBATCH * NBOX * 5 + b * NBOX;
    float* okp = out + (size_t)NBATCH * NBOX * 6 + b * NBOX;

    for (int p = t; p < NBOX; p += 64) {
        bxs[p][0] = ob[p * 4 + 0];
        bxs[p][1] = ob[p * 4 + 1];
        bxs[p][2] = ob[p * 4 + 2];
        bxs[p][3] = ob[p * 4 + 3];
        scs[p] = os[p];
        cl[p]  = oc[p];
    }
    __syncthreads();

    unsigned long long local = 0ull;
    for (int p = t; p < NBOX; p += 64) {
        unsigned long long k =
            ((unsigned long long)__float_as_uint(scs[p]) << 32) | (unsigned)~(unsigned)p;
        if (k > local) local = k;
    }
    #pragma unroll
    for (int off = 32; off > 0; off >>= 1) {
        unsigned long long o = __shfl_xor(local, off);
        if (o > local) local = o;
    }
    unsigned long long kmax = local;

    for (int i = 0; i < NBOX; ++i) {
        int m = (int)(~((unsigned)kmax));
        if (t == 0 && m != i) {
            #pragma unroll
            for (int k = 0; k < 4; ++k) {
                float tmp = bxs[i][k]; bxs[i][k] = bxs[m][k]; bxs[m][k] = tmp;
            }
            float ts = scs[i]; scs[i] = scs[m]; scs[m] = ts;
            float tc = cl[i];  cl[i]  = cl[m];  cl[m]  = tc;
        }
        __syncthreads();

        float b0 = bxs[i][0], b1 = bxs[i][1], b2 = bxs[i][2], b3 = bxs[i][3];
        float area_i = (b2 - b0 + 1.0f) * (b3 - b1 + 1.0f);

        local = 0ull;
        for (int p = i + 1 + t; p < NBOX; p += 64) {
            float x1 = bxs[p][0], y1 = bxs[p][1], x2 = bxs[p][2], y2 = bxs[p][3];
            float areas = (x2 - x1 + 1.0f) * (y2 - y1 + 1.0f);
            float xx1 = fmaxf(b0, x1);
            float yy1 = fmaxf(b1, y1);
            float xx2 = fminf(b2, x2);
            float yy2 = fminf(b3, y2);
            float inter = fmaxf(0.0f, xx2 - xx1 + 1.0f) * fmaxf(0.0f, yy2 - yy1 + 1.0f);
            float iou = inter / (area_i + areas - inter);
            float w = expf(-(iou * iou) / 0.5f);
            float ns = w * scs[p];
            scs[p] = ns;
            unsigned long long k =
                ((unsigned long long)__float_as_uint(ns) << 32) | (unsigned)~(unsigned)p;
            if (k > local) local = k;
        }
        __syncthreads();
        #pragma unroll
        for (int off = 32; off > 0; off >>= 1) {
            unsigned long long o = __shfl_xor(local, off);
            if (o > local) local = o;
        }
        kmax = local;
    }
    __syncthreads();

    for (int p = t; p < NBOX; p += 64) {
        ob[p * 4 + 0] = bxs[p][0];
        ob[p * 4 + 1] = bxs[p][1];
        ob[p * 4 + 2] = bxs[p][2];
        ob[p * 4 + 3] = bxs[p][3];
        oc[p]  = cl[p];
        os[p]  = scs[p];
        okp[p] = (scs[p] > 0.1f) ? 1.0f : 0.0f;
    }
}

extern "C" void kernel_launch(void* const* d_in, const int* in_sizes, int n_in,
                              void* d_out, int out_size, void* d_ws, size_t ws_size,
                              hipStream_t stream) {
    const float* x = (const float*)d_in[0];
    float* out = (float*)d_out;
    if (d_ws != nullptr && ws_size >= WS_NEED) {
        kcollect<<<64 * NPART, 1024, 0, stream>>>(x, (unsigned long long*)d_ws);
        knms6<<<NBATCH, 1024, 0, stream>>>(x, (const unsigned long long*)d_ws, out);
    } else {
        ktopk<<<2 * NBATCH, 1024, 0, stream>>>(x, out);
        knms<<<NBATCH, 64, 0, stream>>>(out);
    }
}